// Round 2
// baseline (421.673 us; speedup 1.0000x reference)
//
#include <hip/hip_runtime.h>
#include <stdint.h>

#define S_LEN 2048
#define HIDDEN 1024
#define NHEADS 16
#define NKVH 4
#define HDIM 64

typedef __bf16 bf16x8 __attribute__((ext_vector_type(8)));
typedef float f32x4 __attribute__((ext_vector_type(4)));
typedef unsigned short ushortx8 __attribute__((ext_vector_type(8)));
typedef unsigned short U16;

static __device__ __forceinline__ float bf2f(U16 u){
    unsigned v = ((unsigned)u) << 16;
    float f;
    __builtin_memcpy(&f, &v, 4);
    return f;
}
static __device__ __forceinline__ U16 f2bf(float f){
    unsigned u;
    __builtin_memcpy(&u, &f, 4);
    u += 0x7FFFu + ((u >> 16) & 1u);   // round-to-nearest-even
    return (U16)(u >> 16);
}

// ---------------------------------------------------------------------------
// Kernel 1: fused QKV projection GEMM (NT) + bias + RoPE. fp32 in, bf16 ws out.
//   X [8192,1024] @ W^T, W = concat(Wq[1024], Wk[256], Wv[256]) along N.
//   128x128 block tile, BK=32, 4 waves each 64x64 (4x4 MFMA 16x16x32).
//   grid (12, 64). RoPE partner d^32 == accumulator tile j^2 (head-aligned).
// ---------------------------------------------------------------------------
#define G_AS 40   // LDS leading stride (elems): 80B rows -> 16B-aligned

__global__ __launch_bounds__(256, 2)
void qkv_kernel(const float* __restrict__ X,
                const float* __restrict__ Wq, const float* __restrict__ Wk, const float* __restrict__ Wv,
                const float* __restrict__ bq, const float* __restrict__ bk, const float* __restrict__ bv,
                const float* __restrict__ cosT, const float* __restrict__ sinT,
                U16* __restrict__ qws, U16* __restrict__ kws, U16* __restrict__ vws)
{
    __shared__ __align__(16) U16 Asm[128 * G_AS];
    __shared__ __align__(16) U16 Bsm[128 * G_AS];

    const int nblk = blockIdx.x;   // 0..11 (0..7 q, 8..9 k, 10..11 v)
    const int mblk = blockIdx.y;   // 0..63
    const int tid  = threadIdx.x;
    const int wave = tid >> 6, lane = tid & 63;
    const int ln = lane & 15, quad = lane >> 4;
    const int wm = wave >> 1, wn = wave & 1;

    const float* Wp; const float* biasp; int region;
    const int nbase = nblk * 128;
    if (nblk < 8)       { Wp = Wq + (size_t)nbase * HIDDEN;          biasp = bq + nbase;          region = 0; }
    else if (nblk < 10) { Wp = Wk + (size_t)(nbase - 1024) * HIDDEN; biasp = bk + (nbase - 1024); region = 1; }
    else                { Wp = Wv + (size_t)(nbase - 1280) * HIDDEN; biasp = bv + (nbase - 1280); region = 2; }
    const float* Xp = X + (size_t)mblk * 128 * HIDDEN;

    f32x4 acc[4][4];
    #pragma unroll
    for (int i = 0; i < 4; i++)
        #pragma unroll
        for (int j = 0; j < 4; j++) acc[i][j] = (f32x4){0.f, 0.f, 0.f, 0.f};

    const int lrow = tid >> 2;          // 0..63
    const int lcol = (tid & 3) * 8;     // 0,8,16,24

    for (int k0 = 0; k0 < HIDDEN; k0 += 32) {
        __syncthreads();
        #pragma unroll
        for (int hh = 0; hh < 2; hh++) {
            int row = lrow + hh * 64;
            const float* sa = Xp + (size_t)row * HIDDEN + k0 + lcol;
            const float* sb = Wp + (size_t)row * HIDDEN + k0 + lcol;
            float4 a0 = *(const float4*)(sa);
            float4 a1 = *(const float4*)(sa + 4);
            float4 b0 = *(const float4*)(sb);
            float4 b1 = *(const float4*)(sb + 4);
            U16 ta[8] = {f2bf(a0.x), f2bf(a0.y), f2bf(a0.z), f2bf(a0.w),
                         f2bf(a1.x), f2bf(a1.y), f2bf(a1.z), f2bf(a1.w)};
            U16 tb[8] = {f2bf(b0.x), f2bf(b0.y), f2bf(b0.z), f2bf(b0.w),
                         f2bf(b1.x), f2bf(b1.y), f2bf(b1.z), f2bf(b1.w)};
            *(uint4*)(&Asm[row * G_AS + lcol]) = *(const uint4*)ta;
            *(uint4*)(&Bsm[row * G_AS + lcol]) = *(const uint4*)tb;
        }
        __syncthreads();

        bf16x8 af[4], bfr[4];
        #pragma unroll
        for (int i = 0; i < 4; i++) {
            af[i]  = *(const bf16x8*)(&Asm[(wm * 64 + i * 16 + ln) * G_AS + quad * 8]);
            bfr[i] = *(const bf16x8*)(&Bsm[(wn * 64 + i * 16 + ln) * G_AS + quad * 8]);
        }
        #pragma unroll
        for (int i = 0; i < 4; i++)
            #pragma unroll
            for (int j = 0; j < 4; j++)
                acc[i][j] = __builtin_amdgcn_mfma_f32_16x16x32_bf16(af[i], bfr[j], acc[i][j], 0, 0, 0);
    }

    // ---- epilogue: bias, RoPE (q,k), scale q by 1/8, scatter to head-major ws
    float bias[4];
    #pragma unroll
    for (int j = 0; j < 4; j++) bias[j] = biasp[wn * 64 + j * 16 + ln];

    #pragma unroll
    for (int i = 0; i < 4; i++) {
        #pragma unroll
        for (int r = 0; r < 4; r++) {
            int m = mblk * 128 + wm * 64 + i * 16 + quad * 4 + r;
            int s = m & (S_LEN - 1), b = m >> 11;
            float vals[4];
            #pragma unroll
            for (int j = 0; j < 4; j++) vals[j] = acc[i][j][r] + bias[j];

            if (region == 2) {      // V: no RoPE
                #pragma unroll
                for (int j = 0; j < 4; j++) {
                    int n2 = nbase - 1280 + wn * 64 + j * 16 + ln;
                    int hh = n2 >> 6, d = n2 & 63;
                    vws[(((size_t)b * NKVH + hh) * S_LEN + s) * HDIM + d] = f2bf(vals[j]);
                }
            } else {
                float outv[4];
                #pragma unroll
                for (int j = 0; j < 4; j++) {
                    int d = (wn * 64 + j * 16 + ln) & 63;
                    float c  = cosT[s * HDIM + d];
                    float sn = sinT[s * HDIM + d];
                    float partner = vals[j ^ 2];           // element at d^32, same lane/reg
                    float rot = (d < 32) ? -partner : partner;
                    outv[j] = vals[j] * c + rot * sn;
                }
                if (region == 0) {  // Q: fold softmax scale 1/8 (exact pow2)
                    #pragma unroll
                    for (int j = 0; j < 4; j++) {
                        int n = nbase + wn * 64 + j * 16 + ln;
                        int hh = n >> 6, d = n & 63;
                        qws[(((size_t)b * NHEADS + hh) * S_LEN + s) * HDIM + d] = f2bf(outv[j] * 0.125f);
                    }
                } else {            // K
                    #pragma unroll
                    for (int j = 0; j < 4; j++) {
                        int n2 = nbase - 1024 + wn * 64 + j * 16 + ln;
                        int hh = n2 >> 6, d = n2 & 63;
                        kws[(((size_t)b * NKVH + hh) * S_LEN + s) * HDIM + d] = f2bf(outv[j]);
                    }
                }
            }
        }
    }
}

// ---------------------------------------------------------------------------
// Kernel 2: flash attention (no mask). grid (16 qtiles, 64 head-instances).
//   Block = 128 Q-rows; wave w owns rows [w*32, w*32+32). K-tiles of 128.
//   All bf16 in/out via workspace. Unchanged from prior structure.
// ---------------------------------------------------------------------------
#define A_KS  72    // K-tile LDS stride (144B rows, 16B aligned)
#define A_VTS 136   // V^T LDS stride (272B rows)
#define A_PS  136   // P LDS stride

__global__ __launch_bounds__(256, 2)
void attn_kernel(const U16* __restrict__ qws, const U16* __restrict__ kws,
                 const U16* __restrict__ vws, U16* __restrict__ aws)
{
    __shared__ __align__(16) U16 Ksm[128 * A_KS];
    __shared__ __align__(16) U16 VTsm[64 * A_VTS];
    __shared__ __align__(16) U16 Psm[4][32 * A_PS];

    const int qt = blockIdx.x;              // 0..15
    const int hg = blockIdx.y;              // 0..63 = b*16+h
    const int b = hg >> 4, h = hg & 15, hkv = h >> 2;
    const U16* Qh = qws + (size_t)hg * S_LEN * HDIM;
    const U16* Kh = kws + (size_t)(b * NKVH + hkv) * S_LEN * HDIM;
    const U16* Vh = vws + (size_t)(b * NKVH + hkv) * S_LEN * HDIM;

    const int tid = threadIdx.x;
    const int wave = tid >> 6, lane = tid & 63;
    const int ln = lane & 15, quad = lane >> 4;

    // Q fragments for this wave's 32 rows, resident all kernel
    bf16x8 qf[2][2];
    #pragma unroll
    for (int i = 0; i < 2; i++)
        #pragma unroll
        for (int ks = 0; ks < 2; ks++) {
            int row = qt * 128 + wave * 32 + i * 16 + ln;
            qf[i][ks] = *(const bf16x8*)(Qh + (size_t)row * HDIM + ks * 32 + quad * 8);
        }

    float mi[2][4], li[2][4];
    f32x4 o[2][4];
    #pragma unroll
    for (int i = 0; i < 2; i++)
        #pragma unroll
        for (int r = 0; r < 4; r++) { mi[i][r] = -1e30f; li[i][r] = 0.f; }
    #pragma unroll
    for (int i = 0; i < 2; i++)
        #pragma unroll
        for (int n = 0; n < 4; n++) o[i][n] = (f32x4){0.f, 0.f, 0.f, 0.f};

    for (int kt = 0; kt < 16; kt++) {
        __syncthreads();   // prev iter done with K/VT
        {   // K tile: 128x64
            int rowb = tid >> 2;
            int c0 = (tid & 3) * 16;
            #pragma unroll
            for (int hh = 0; hh < 2; hh++) {
                int row = rowb + hh * 64;
                const U16* src = Kh + (size_t)(kt * 128 + row) * HDIM + c0;
                *(uint4*)(&Ksm[row * A_KS + c0])     = *(const uint4*)(src);
                *(uint4*)(&Ksm[row * A_KS + c0 + 8]) = *(const uint4*)(src + 8);
            }
            // V tile transposed: VT[d][key]
            #pragma unroll
            for (int it = 0; it < 4; it++) {
                int idx = tid + it * 256;
                int sv = idx & 127;
                int d0 = (idx >> 7) * 8;
                ushortx8 dv = *(const ushortx8*)(Vh + (size_t)(kt * 128 + sv) * HDIM + d0);
                #pragma unroll
                for (int jj = 0; jj < 8; jj++) VTsm[(d0 + jj) * A_VTS + sv] = dv[jj];
            }
        }
        __syncthreads();

        // scores: 32x128 per wave (scale pre-folded into q)
        f32x4 sc[2][8];
        #pragma unroll
        for (int j = 0; j < 8; j++) {
            bf16x8 kf0 = *(const bf16x8*)(&Ksm[(j * 16 + ln) * A_KS + quad * 8]);
            bf16x8 kf1 = *(const bf16x8*)(&Ksm[(j * 16 + ln) * A_KS + 32 + quad * 8]);
            #pragma unroll
            for (int i = 0; i < 2; i++) {
                f32x4 z = (f32x4){0.f, 0.f, 0.f, 0.f};
                z = __builtin_amdgcn_mfma_f32_16x16x32_bf16(qf[i][0], kf0, z, 0, 0, 0);
                z = __builtin_amdgcn_mfma_f32_16x16x32_bf16(qf[i][1], kf1, z, 0, 0, 0);
                sc[i][j] = z;
            }
        }

        // online softmax
        #pragma unroll
        for (int i = 0; i < 2; i++) {
            float alpha[4];
            #pragma unroll
            for (int r = 0; r < 4; r++) {
                float v = fmaxf(fmaxf(fmaxf(sc[i][0][r], sc[i][1][r]), fmaxf(sc[i][2][r], sc[i][3][r])),
                                fmaxf(fmaxf(sc[i][4][r], sc[i][5][r]), fmaxf(sc[i][6][r], sc[i][7][r])));
                v = fmaxf(v, __shfl_xor(v, 1));
                v = fmaxf(v, __shfl_xor(v, 2));
                v = fmaxf(v, __shfl_xor(v, 4));
                v = fmaxf(v, __shfl_xor(v, 8));
                float mnew = fmaxf(mi[i][r], v);
                alpha[r] = __expf(mi[i][r] - mnew);
                mi[i][r] = mnew;
            }
            float rsum[4] = {0.f, 0.f, 0.f, 0.f};
            #pragma unroll
            for (int j = 0; j < 8; j++)
                #pragma unroll
                for (int r = 0; r < 4; r++) {
                    float p = __expf(sc[i][j][r] - mi[i][r]);
                    sc[i][j][r] = p;
                    rsum[r] += p;
                }
            #pragma unroll
            for (int r = 0; r < 4; r++) {
                float t = rsum[r];
                t += __shfl_xor(t, 1);
                t += __shfl_xor(t, 2);
                t += __shfl_xor(t, 4);
                t += __shfl_xor(t, 8);
                li[i][r] = li[i][r] * alpha[r] + t;
            }
            #pragma unroll
            for (int n = 0; n < 4; n++)
                #pragma unroll
                for (int r = 0; r < 4; r++) o[i][n][r] *= alpha[r];
            // P -> LDS (wave-private), bf16
            #pragma unroll
            for (int j = 0; j < 8; j++)
                #pragma unroll
                for (int r = 0; r < 4; r++)
                    Psm[wave][(i * 16 + quad * 4 + r) * A_PS + j * 16 + ln] = f2bf(sc[i][j][r]);
        }
        __syncthreads();   // P visible (uniform barrier before PV)

        // O += P @ V  (A = P from LDS, B = V^T rows contiguous)
        #pragma unroll
        for (int ks2 = 0; ks2 < 4; ks2++) {
            bf16x8 pf[2];
            #pragma unroll
            for (int i = 0; i < 2; i++)
                pf[i] = *(const bf16x8*)(&Psm[wave][(i * 16 + ln) * A_PS + ks2 * 32 + quad * 8]);
            #pragma unroll
            for (int n = 0; n < 4; n++) {
                bf16x8 vf = *(const bf16x8*)(&VTsm[(n * 16 + ln) * A_VTS + ks2 * 32 + quad * 8]);
                #pragma unroll
                for (int i = 0; i < 2; i++)
                    o[i][n] = __builtin_amdgcn_mfma_f32_16x16x32_bf16(pf[i], vf, o[i][n], 0, 0, 0);
            }
        }
    }

    // epilogue: normalize, write [B,S,NH*HD] bf16 workspace
    #pragma unroll
    for (int i = 0; i < 2; i++)
        #pragma unroll
        for (int n = 0; n < 4; n++)
            #pragma unroll
            for (int r = 0; r < 4; r++) {
                int qrow = qt * 128 + wave * 32 + i * 16 + quad * 4 + r;
                int col = h * HDIM + n * 16 + ln;
                aws[((size_t)b * S_LEN + qrow) * (NHEADS * HDIM) + col] = f2bf(o[i][n][r] / li[i][r]);
            }
}

// ---------------------------------------------------------------------------
// Kernel 3: output projection GEMM (NT) + bias. A = aws (bf16), Wo fp32,
// out fp32. grid (8, 64).
// ---------------------------------------------------------------------------
__global__ __launch_bounds__(256, 2)
void proj_kernel(const U16* __restrict__ A, const float* __restrict__ Wo,
                 const float* __restrict__ bo, float* __restrict__ out)
{
    __shared__ __align__(16) U16 Asm[128 * G_AS];
    __shared__ __align__(16) U16 Bsm[128 * G_AS];

    const int nblk = blockIdx.x;   // 0..7
    const int mblk = blockIdx.y;   // 0..63
    const int tid  = threadIdx.x;
    const int wave = tid >> 6, lane = tid & 63;
    const int ln = lane & 15, quad = lane >> 4;
    const int wm = wave >> 1, wn = wave & 1;

    const int nbase = nblk * 128;
    const float* Wp = Wo + (size_t)nbase * HIDDEN;
    const U16* Ap = A + (size_t)mblk * 128 * HIDDEN;

    f32x4 acc[4][4];
    #pragma unroll
    for (int i = 0; i < 4; i++)
        #pragma unroll
        for (int j = 0; j < 4; j++) acc[i][j] = (f32x4){0.f, 0.f, 0.f, 0.f};

    const int lrow = tid >> 2;
    const int lcol = (tid & 3) * 8;

    for (int k0 = 0; k0 < HIDDEN; k0 += 32) {
        __syncthreads();
        #pragma unroll
        for (int hh = 0; hh < 2; hh++) {
            int row = lrow + hh * 64;
            *(uint4*)(&Asm[row * G_AS + lcol]) = *(const uint4*)(Ap + (size_t)row * HIDDEN + k0 + lcol);
            const float* sb = Wp + (size_t)row * HIDDEN + k0 + lcol;
            float4 b0 = *(const float4*)(sb);
            float4 b1 = *(const float4*)(sb + 4);
            U16 tb[8] = {f2bf(b0.x), f2bf(b0.y), f2bf(b0.z), f2bf(b0.w),
                         f2bf(b1.x), f2bf(b1.y), f2bf(b1.z), f2bf(b1.w)};
            *(uint4*)(&Bsm[row * G_AS + lcol]) = *(const uint4*)tb;
        }
        __syncthreads();

        bf16x8 af[4], bfr[4];
        #pragma unroll
        for (int i = 0; i < 4; i++) {
            af[i]  = *(const bf16x8*)(&Asm[(wm * 64 + i * 16 + ln) * G_AS + quad * 8]);
            bfr[i] = *(const bf16x8*)(&Bsm[(wn * 64 + i * 16 + ln) * G_AS + quad * 8]);
        }
        #pragma unroll
        for (int i = 0; i < 4; i++)
            #pragma unroll
            for (int j = 0; j < 4; j++)
                acc[i][j] = __builtin_amdgcn_mfma_f32_16x16x32_bf16(af[i], bfr[j], acc[i][j], 0, 0, 0);
    }

    float bias[4];
    #pragma unroll
    for (int j = 0; j < 4; j++) bias[j] = bo[nbase + wn * 64 + j * 16 + ln];

    #pragma unroll
    for (int i = 0; i < 4; i++)
        #pragma unroll
        for (int r = 0; r < 4; r++) {
            int m = mblk * 128 + wm * 64 + i * 16 + quad * 4 + r;
            #pragma unroll
            for (int j = 0; j < 4; j++) {
                int n = nbase + wn * 64 + j * 16 + ln;
                out[(size_t)m * HIDDEN + n] = acc[i][j][r] + bias[j];
            }
        }
}

// ---------------------------------------------------------------------------
extern "C" void kernel_launch(void* const* d_in, const int* in_sizes, int n_in,
                              void* d_out, int out_size, void* d_ws, size_t ws_size,
                              hipStream_t stream)
{
    const float* X    = (const float*)d_in[0];
    const float* cosT = (const float*)d_in[1];
    const float* sinT = (const float*)d_in[2];
    const float* Wq   = (const float*)d_in[3];
    const float* bq   = (const float*)d_in[4];
    const float* Wk   = (const float*)d_in[5];
    const float* bk   = (const float*)d_in[6];
    const float* Wv   = (const float*)d_in[7];
    const float* bv   = (const float*)d_in[8];
    const float* Wo   = (const float*)d_in[9];
    const float* bo   = (const float*)d_in[10];
    float* out = (float*)d_out;

    // workspace layout (bf16 elems): q[4*16*2048*64] k[4*4*2048*64] v[same] attn[4*2048*1024]
    U16* qws = (U16*)d_ws;
    U16* kws = qws + (size_t)4 * NHEADS * S_LEN * HDIM;
    U16* vws = kws + (size_t)4 * NKVH * S_LEN * HDIM;
    U16* aws = vws + (size_t)4 * NKVH * S_LEN * HDIM;

    qkv_kernel<<<dim3(12, 64), 256, 0, stream>>>(X, Wq, Wk, Wv, bq, bk, bv, cosT, sinT, qws, kws, vws);
    attn_kernel<<<dim3(16, 64), 256, 0, stream>>>(qws, kws, vws, aws);
    proj_kernel<<<dim3(8, 64), 256, 0, stream>>>(aws, Wo, bo, out);
}

// Round 3
// 349.045 us; speedup vs baseline: 1.2081x; 1.2081x over previous
//
#include <hip/hip_runtime.h>
#include <stdint.h>

#define S_LEN 2048
#define HIDDEN 1024
#define NHEADS 16
#define NKVH 4
#define HDIM 64

typedef __bf16 bf16x8 __attribute__((ext_vector_type(8)));
typedef float f32x4 __attribute__((ext_vector_type(4)));
typedef unsigned short ushortx8 __attribute__((ext_vector_type(8)));
typedef unsigned short U16;

// ---- workspace layout (bf16 elems) -----------------------------------------
#define OFF_XB   0u          // 8192*1024            (aliased by aws later)
#define OFF_WQB  8388608u    // 1024*1024
#define OFF_WKB  9437184u    // 256*1024
#define OFF_WVB  9699328u    // 256*1024
#define OFF_WOB  9961472u    // 1024*1024
#define OFF_Q    11010048u   // 4*16*2048*64
#define OFF_K    19398656u   // 4*4*2048*64
#define OFF_V    21495808u   // 4*4*2048*64
#define OFF_AWS  OFF_XB      // alias: X dead after qkv, aws needs 8388608

static __device__ __forceinline__ U16 f2bf(float f){
    unsigned u;
    __builtin_memcpy(&u, &f, 4);
    u += 0x7FFFu + ((u >> 16) & 1u);   // RNE
    return (U16)(u >> 16);
}
static __device__ __forceinline__ uint32_t pkbf(float lo, float hi){
    uint32_t a, b;
    __builtin_memcpy(&a, &lo, 4); a += 0x7FFFu + ((a >> 16) & 1u);
    __builtin_memcpy(&b, &hi, 4); b += 0x7FFFu + ((b >> 16) & 1u);
    return (a >> 16) | (b & 0xFFFF0000u);
}

typedef __attribute__((address_space(3))) uint32_t lds_u32;
typedef const __attribute__((address_space(1))) uint32_t glb_u32;
static __device__ __forceinline__ void glds16(const U16* g, U16* l){
    __builtin_amdgcn_global_load_lds((glb_u32*)g, (lds_u32*)l, 16, 0, 0);
}

// ---------------------------------------------------------------------------
// Kernel 0: fp32 -> bf16 convert of X, Wq, Wk, Wv, Wo into workspace.
// grid 10752 x 256, one float4 per thread. Memory-bound (~11 us).
// ---------------------------------------------------------------------------
__global__ void conv_kernel(const float* __restrict__ X,  const float* __restrict__ Wq,
                            const float* __restrict__ Wk, const float* __restrict__ Wv,
                            const float* __restrict__ Wo, U16* __restrict__ dst)
{
    size_t i4 = (size_t)blockIdx.x * 256 + threadIdx.x;   // 0..2752511
    size_t e = i4 * 4;
    const float* s;
    if (e < 8388608u)       s = X  + e;
    else if (e < 9437184u)  s = Wq + (e - 8388608u);
    else if (e < 9699328u)  s = Wk + (e - 9437184u);
    else if (e < 9961472u)  s = Wv + (e - 9699328u);
    else                    s = Wo + (e - 9961472u);
    float4 v = *(const float4*)s;
    uint2 o; o.x = pkbf(v.x, v.y); o.y = pkbf(v.z, v.w);
    *(uint2*)(dst + e) = o;
}

// ---------------------------------------------------------------------------
// Kernel 1: QKV GEMM (NT) + bias + RoPE. bf16 inputs (pre-converted),
// global_load_lds width-16 staging (m97 structure), BK=32. grid (12, 64).
// ---------------------------------------------------------------------------
__global__ __launch_bounds__(256, 3)
void qkv_kernel(const U16* __restrict__ Xb,
                const U16* __restrict__ Wqb, const U16* __restrict__ Wkb, const U16* __restrict__ Wvb,
                const float* __restrict__ bq, const float* __restrict__ bk, const float* __restrict__ bv,
                const float* __restrict__ cosT, const float* __restrict__ sinT,
                U16* __restrict__ qws, U16* __restrict__ kws, U16* __restrict__ vws)
{
    __shared__ __align__(16) U16 Asm[128 * 32];   // 8 KB, stride 32 (glds: no pad)
    __shared__ __align__(16) U16 Bsm[128 * 32];

    const int nblk = blockIdx.x;   // 0..11 (0..7 q, 8..9 k, 10..11 v)
    const int mblk = blockIdx.y;   // 0..63
    const int tid  = threadIdx.x;
    const int wave = tid >> 6, lane = tid & 63;
    const int ln = lane & 15, quad = lane >> 4;
    const int wm = wave >> 1, wn = wave & 1;

    const U16* Wp; const float* biasp; int region;
    const int nbase = nblk * 128;
    if (nblk < 8)       { Wp = Wqb + (size_t)nbase * HIDDEN;          biasp = bq + nbase;          region = 0; }
    else if (nblk < 10) { Wp = Wkb + (size_t)(nbase - 1024) * HIDDEN; biasp = bk + (nbase - 1024); region = 1; }
    else                { Wp = Wvb + (size_t)(nbase - 1280) * HIDDEN; biasp = bv + (nbase - 1280); region = 2; }
    const U16* Xp = Xb + (size_t)mblk * 128 * HIDDEN;

    f32x4 acc[4][4];
    #pragma unroll
    for (int i = 0; i < 4; i++)
        #pragma unroll
        for (int j = 0; j < 4; j++) acc[i][j] = (f32x4){0.f, 0.f, 0.f, 0.f};

    const int srow = wave * 32 + (lane >> 2);   // +t*16
    const int scol = (lane & 3) * 8;

    for (int k0 = 0; k0 < HIDDEN; k0 += 32) {
        __syncthreads();
        glds16(Xp + (size_t)(srow)      * HIDDEN + k0 + scol, &Asm[(wave * 32)      * 32]);
        glds16(Xp + (size_t)(srow + 16) * HIDDEN + k0 + scol, &Asm[(wave * 32 + 16) * 32]);
        glds16(Wp + (size_t)(srow)      * HIDDEN + k0 + scol, &Bsm[(wave * 32)      * 32]);
        glds16(Wp + (size_t)(srow + 16) * HIDDEN + k0 + scol, &Bsm[(wave * 32 + 16) * 32]);
        __syncthreads();

        bf16x8 af[4], bfr[4];
        #pragma unroll
        for (int i = 0; i < 4; i++) {
            af[i]  = *(const bf16x8*)(&Asm[(wm * 64 + i * 16 + ln) * 32 + quad * 8]);
            bfr[i] = *(const bf16x8*)(&Bsm[(wn * 64 + i * 16 + ln) * 32 + quad * 8]);
        }
        #pragma unroll
        for (int i = 0; i < 4; i++)
            #pragma unroll
            for (int j = 0; j < 4; j++)
                acc[i][j] = __builtin_amdgcn_mfma_f32_16x16x32_bf16(af[i], bfr[j], acc[i][j], 0, 0, 0);
    }

    float bias[4];
    #pragma unroll
    for (int j = 0; j < 4; j++) bias[j] = biasp[wn * 64 + j * 16 + ln];

    #pragma unroll
    for (int i = 0; i < 4; i++) {
        #pragma unroll
        for (int r = 0; r < 4; r++) {
            int m = mblk * 128 + wm * 64 + i * 16 + quad * 4 + r;
            int s = m & (S_LEN - 1), b = m >> 11;
            float vals[4];
            #pragma unroll
            for (int j = 0; j < 4; j++) vals[j] = acc[i][j][r] + bias[j];

            if (region == 2) {      // V: no RoPE
                #pragma unroll
                for (int j = 0; j < 4; j++) {
                    int n2 = nbase - 1280 + wn * 64 + j * 16 + ln;
                    int hh = n2 >> 6, d = n2 & 63;
                    vws[(((size_t)b * NKVH + hh) * S_LEN + s) * HDIM + d] = f2bf(vals[j]);
                }
            } else {
                float outv[4];
                #pragma unroll
                for (int j = 0; j < 4; j++) {
                    int d = (wn * 64 + j * 16 + ln) & 63;
                    float c  = cosT[s * HDIM + d];
                    float sn = sinT[s * HDIM + d];
                    float partner = vals[j ^ 2];           // element at d^32, same lane/reg
                    float rot = (d < 32) ? -partner : partner;
                    outv[j] = vals[j] * c + rot * sn;
                }
                if (region == 0) {  // Q: fold softmax scale 1/8
                    #pragma unroll
                    for (int j = 0; j < 4; j++) {
                        int n = nbase + wn * 64 + j * 16 + ln;
                        int hh = n >> 6, d = n & 63;
                        qws[(((size_t)b * NHEADS + hh) * S_LEN + s) * HDIM + d] = f2bf(outv[j] * 0.125f);
                    }
                } else {            // K
                    #pragma unroll
                    for (int j = 0; j < 4; j++) {
                        int n2 = nbase - 1024 + wn * 64 + j * 16 + ln;
                        int hh = n2 >> 6, d = n2 & 63;
                        kws[(((size_t)b * NKVH + hh) * S_LEN + s) * HDIM + d] = f2bf(outv[j]);
                    }
                }
            }
        }
    }
}

// ---------------------------------------------------------------------------
// Kernel 2: flash attention, operand-swapped (S^T = K*Q^T, O^T = V^T*P^T).
// No P LDS round-trip: P^T B-fragments built by ds_bpermute repack.
// Register prefetch of next K/V tile. 2 barriers/K-tile. LDS 35.8 KB -> 3 blk/CU.
// ---------------------------------------------------------------------------
#define A_KS  72    // K-tile LDS stride
#define A_VTS 136   // V^T LDS stride

__global__ __launch_bounds__(256, 3)
void attn_kernel(const U16* __restrict__ qws, const U16* __restrict__ kws,
                 const U16* __restrict__ vws, U16* __restrict__ aws)
{
    __shared__ __align__(16) U16 Ksm[128 * A_KS];    // 18432 B
    __shared__ __align__(16) U16 VTsm[64 * A_VTS];   // 17408 B

    const int qt = blockIdx.x;              // 0..15
    const int hg = blockIdx.y;              // 0..63 = b*16+h
    const int b = hg >> 4, h = hg & 15, hkv = h >> 2;
    const U16* Qh = qws + (size_t)hg * S_LEN * HDIM;
    const U16* Kh = kws + (size_t)(b * NKVH + hkv) * S_LEN * HDIM;
    const U16* Vh = vws + (size_t)(b * NKVH + hkv) * S_LEN * HDIM;

    const int tid = threadIdx.x;
    const int wave = tid >> 6, lane = tid & 63;
    const int ln = lane & 15, quad = lane >> 4;

    // Q fragments (B-operand layout == same bytes as before): q = wave*32+16i+ln
    bf16x8 qf[2][2];
    #pragma unroll
    for (int i = 0; i < 2; i++)
        #pragma unroll
        for (int ks = 0; ks < 2; ks++) {
            int row = qt * 128 + wave * 32 + i * 16 + ln;
            qf[i][ks] = *(const bf16x8*)(Qh + (size_t)row * HDIM + ks * 32 + quad * 8);
        }

    float mi[2] = {-1e30f, -1e30f}, li[2] = {0.f, 0.f};
    f32x4 o_t[4][2];   // O^T[d-block n][q-block i]
    #pragma unroll
    for (int n = 0; n < 4; n++)
        #pragma unroll
        for (int i = 0; i < 2; i++) o_t[n][i] = (f32x4){0.f, 0.f, 0.f, 0.f};

    // staging addressing
    const int krow = tid >> 2;              // 0..63 (and +64)
    const int kc0  = (tid & 3) * 16;
    // V transpose scatter: idx = tid + it*256
    // prefetch registers
    uint4 kreg[2][2];
    ushortx8 vreg[4];

    // prologue: load tile 0
    #pragma unroll
    for (int hh = 0; hh < 2; hh++) {
        const U16* src = Kh + (size_t)(krow + hh * 64) * HDIM + kc0;
        kreg[hh][0] = *(const uint4*)(src);
        kreg[hh][1] = *(const uint4*)(src + 8);
    }
    #pragma unroll
    for (int it = 0; it < 4; it++) {
        int idx = tid + it * 256;
        vreg[it] = *(const ushortx8*)(Vh + (size_t)(idx & 127) * HDIM + ((idx >> 7) * 8));
    }

    const int srclo = ln + 16 * (2 * (quad & 1));   // bpermute source lanes
    const bool oddblk = (quad >= 2);

    for (int kt = 0; kt < 16; kt++) {
        __syncthreads();   // prev iter readers done with Ksm/VTsm
        // regs -> LDS
        #pragma unroll
        for (int hh = 0; hh < 2; hh++) {
            int row = krow + hh * 64;
            *(uint4*)(&Ksm[row * A_KS + kc0])     = kreg[hh][0];
            *(uint4*)(&Ksm[row * A_KS + kc0 + 8]) = kreg[hh][1];
        }
        #pragma unroll
        for (int it = 0; it < 4; it++) {
            int idx = tid + it * 256;
            int sv = idx & 127, d0 = (idx >> 7) * 8;
            #pragma unroll
            for (int jj = 0; jj < 8; jj++) VTsm[(d0 + jj) * A_VTS + sv] = vreg[it][jj];
        }
        // prefetch next tile into regs (latency hidden under compute)
        if (kt < 15) {
            #pragma unroll
            for (int hh = 0; hh < 2; hh++) {
                const U16* src = Kh + (size_t)((kt + 1) * 128 + krow + hh * 64) * HDIM + kc0;
                kreg[hh][0] = *(const uint4*)(src);
                kreg[hh][1] = *(const uint4*)(src + 8);
            }
            #pragma unroll
            for (int it = 0; it < 4; it++) {
                int idx = tid + it * 256;
                vreg[it] = *(const ushortx8*)(Vh + (size_t)((kt + 1) * 128 + (idx & 127)) * HDIM + ((idx >> 7) * 8));
            }
        }
        __syncthreads();   // LDS visible

        // two 64-key halves, online softmax per half (keeps st live range small)
        #pragma unroll
        for (int h2 = 0; h2 < 2; h2++) {
            // S^T: st[i][j4][r] = S[q=16i+ln][key = 16*(4*h2+j4) + quad*4 + r]
            f32x4 st[2][4];
            #pragma unroll
            for (int j4 = 0; j4 < 4; j4++) {
                int j = h2 * 4 + j4;
                bf16x8 kf0 = *(const bf16x8*)(&Ksm[(j * 16 + ln) * A_KS + quad * 8]);
                bf16x8 kf1 = *(const bf16x8*)(&Ksm[(j * 16 + ln) * A_KS + 32 + quad * 8]);
                #pragma unroll
                for (int i = 0; i < 2; i++) {
                    f32x4 z = (f32x4){0.f, 0.f, 0.f, 0.f};
                    z = __builtin_amdgcn_mfma_f32_16x16x32_bf16(kf0, qf[i][0], z, 0, 0, 0);
                    z = __builtin_amdgcn_mfma_f32_16x16x32_bf16(kf1, qf[i][1], z, 0, 0, 0);
                    st[i][j4] = z;
                }
            }
            // online softmax (row stats per lane: query = 16i+ln)
            uint32_t pk0[2][4], pk1[2][4];
            #pragma unroll
            for (int i = 0; i < 2; i++) {
                float v = st[i][0][0];
                #pragma unroll
                for (int j4 = 0; j4 < 4; j4++)
                    #pragma unroll
                    for (int r = 0; r < 4; r++) v = fmaxf(v, st[i][j4][r]);
                v = fmaxf(v, __shfl_xor(v, 16));
                v = fmaxf(v, __shfl_xor(v, 32));
                float mnew = fmaxf(mi[i], v);
                float alpha = __expf(mi[i] - mnew);
                mi[i] = mnew;
                float rs = 0.f;
                #pragma unroll
                for (int j4 = 0; j4 < 4; j4++)
                    #pragma unroll
                    for (int r = 0; r < 4; r++) {
                        float p = __expf(st[i][j4][r] - mnew);
                        st[i][j4][r] = p;
                        rs += p;
                    }
                rs += __shfl_xor(rs, 16);
                rs += __shfl_xor(rs, 32);
                li[i] = li[i] * alpha + rs;
                #pragma unroll
                for (int n = 0; n < 4; n++) o_t[n][i] *= alpha;
                #pragma unroll
                for (int j4 = 0; j4 < 4; j4++) {
                    pk0[i][j4] = pkbf(st[i][j4][0], st[i][j4][1]);
                    pk1[i][j4] = pkbf(st[i][j4][2], st[i][j4][3]);
                }
            }
            // PV: O^T += V^T * P^T, two 32-key chunks in this half
            #pragma unroll
            for (int c4 = 0; c4 < 2; c4++) {
                bf16x8 bfrag[2];
                #pragma unroll
                for (int i = 0; i < 2; i++) {
                    uint32_t w0e = __shfl(pk0[i][2 * c4],     srclo);
                    uint32_t w0o = __shfl(pk0[i][2 * c4 + 1], srclo);
                    uint32_t w1e = __shfl(pk1[i][2 * c4],     srclo);
                    uint32_t w1o = __shfl(pk1[i][2 * c4 + 1], srclo);
                    uint32_t w2e = __shfl(pk0[i][2 * c4],     srclo + 16);
                    uint32_t w2o = __shfl(pk0[i][2 * c4 + 1], srclo + 16);
                    uint32_t w3e = __shfl(pk1[i][2 * c4],     srclo + 16);
                    uint32_t w3o = __shfl(pk1[i][2 * c4 + 1], srclo + 16);
                    uint32_t w[4];
                    w[0] = oddblk ? w0o : w0e;
                    w[1] = oddblk ? w1o : w1e;
                    w[2] = oddblk ? w2o : w2e;
                    w[3] = oddblk ? w3o : w3e;
                    __builtin_memcpy(&bfrag[i], w, 16);
                }
                int c = h2 * 2 + c4;
                #pragma unroll
                for (int n = 0; n < 4; n++) {
                    bf16x8 vf = *(const bf16x8*)(&VTsm[(n * 16 + ln) * A_VTS + c * 32 + quad * 8]);
                    #pragma unroll
                    for (int i = 0; i < 2; i++)
                        o_t[n][i] = __builtin_amdgcn_mfma_f32_16x16x32_bf16(vf, bfrag[i], o_t[n][i], 0, 0, 0);
                }
            }
        }
    }

    // epilogue: normalize, write O (8B stores, d-contiguous)
    float inv_li[2] = {1.f / li[0], 1.f / li[1]};
    #pragma unroll
    for (int n = 0; n < 4; n++)
        #pragma unroll
        for (int i = 0; i < 2; i++) {
            int q = qt * 128 + wave * 32 + i * 16 + ln;
            int d = n * 16 + quad * 4;
            uint2 w;
            w.x = pkbf(o_t[n][i][0] * inv_li[i], o_t[n][i][1] * inv_li[i]);
            w.y = pkbf(o_t[n][i][2] * inv_li[i], o_t[n][i][3] * inv_li[i]);
            *(uint2*)(aws + ((size_t)b * S_LEN + q) * (NHEADS * HDIM) + h * HDIM + d) = w;
        }
}

// ---------------------------------------------------------------------------
// Kernel 3: output projection GEMM (NT) + bias. bf16 A/W via global_load_lds,
// fp32 out. grid (8, 64).
// ---------------------------------------------------------------------------
__global__ __launch_bounds__(256, 3)
void proj_kernel(const U16* __restrict__ A, const U16* __restrict__ Wob,
                 const float* __restrict__ bo, float* __restrict__ out)
{
    __shared__ __align__(16) U16 Asm[128 * 32];
    __shared__ __align__(16) U16 Bsm[128 * 32];

    const int nblk = blockIdx.x;   // 0..7
    const int mblk = blockIdx.y;   // 0..63
    const int tid  = threadIdx.x;
    const int wave = tid >> 6, lane = tid & 63;
    const int ln = lane & 15, quad = lane >> 4;
    const int wm = wave >> 1, wn = wave & 1;

    const int nbase = nblk * 128;
    const U16* Wp = Wob + (size_t)nbase * HIDDEN;
    const U16* Ap = A + (size_t)mblk * 128 * HIDDEN;

    f32x4 acc[4][4];
    #pragma unroll
    for (int i = 0; i < 4; i++)
        #pragma unroll
        for (int j = 0; j < 4; j++) acc[i][j] = (f32x4){0.f, 0.f, 0.f, 0.f};

    const int srow = wave * 32 + (lane >> 2);
    const int scol = (lane & 3) * 8;

    for (int k0 = 0; k0 < HIDDEN; k0 += 32) {
        __syncthreads();
        glds16(Ap + (size_t)(srow)      * HIDDEN + k0 + scol, &Asm[(wave * 32)      * 32]);
        glds16(Ap + (size_t)(srow + 16) * HIDDEN + k0 + scol, &Asm[(wave * 32 + 16) * 32]);
        glds16(Wp + (size_t)(srow)      * HIDDEN + k0 + scol, &Bsm[(wave * 32)      * 32]);
        glds16(Wp + (size_t)(srow + 16) * HIDDEN + k0 + scol, &Bsm[(wave * 32 + 16) * 32]);
        __syncthreads();

        bf16x8 af[4], bfr[4];
        #pragma unroll
        for (int i = 0; i < 4; i++) {
            af[i]  = *(const bf16x8*)(&Asm[(wm * 64 + i * 16 + ln) * 32 + quad * 8]);
            bfr[i] = *(const bf16x8*)(&Bsm[(wn * 64 + i * 16 + ln) * 32 + quad * 8]);
        }
        #pragma unroll
        for (int i = 0; i < 4; i++)
            #pragma unroll
            for (int j = 0; j < 4; j++)
                acc[i][j] = __builtin_amdgcn_mfma_f32_16x16x32_bf16(af[i], bfr[j], acc[i][j], 0, 0, 0);
    }

    float bias[4];
    #pragma unroll
    for (int j = 0; j < 4; j++) bias[j] = bo[nbase + wn * 64 + j * 16 + ln];

    #pragma unroll
    for (int i = 0; i < 4; i++)
        #pragma unroll
        for (int r = 0; r < 4; r++) {
            int m = mblk * 128 + wm * 64 + i * 16 + quad * 4 + r;
            #pragma unroll
            for (int j = 0; j < 4; j++) {
                int n = nbase + wn * 64 + j * 16 + ln;
                out[(size_t)m * HIDDEN + n] = acc[i][j][r] + bias[j];
            }
        }
}

// ---------------------------------------------------------------------------
extern "C" void kernel_launch(void* const* d_in, const int* in_sizes, int n_in,
                              void* d_out, int out_size, void* d_ws, size_t ws_size,
                              hipStream_t stream)
{
    const float* X    = (const float*)d_in[0];
    const float* cosT = (const float*)d_in[1];
    const float* sinT = (const float*)d_in[2];
    const float* Wq   = (const float*)d_in[3];
    const float* bq   = (const float*)d_in[4];
    const float* Wk   = (const float*)d_in[5];
    const float* bk   = (const float*)d_in[6];
    const float* Wv   = (const float*)d_in[7];
    const float* bv   = (const float*)d_in[8];
    const float* Wo   = (const float*)d_in[9];
    const float* bo   = (const float*)d_in[10];
    float* out = (float*)d_out;

    U16* wsb = (U16*)d_ws;
    U16* Xb  = wsb + OFF_XB;
    U16* Wqb = wsb + OFF_WQB;
    U16* Wkb = wsb + OFF_WKB;
    U16* Wvb = wsb + OFF_WVB;
    U16* Wob = wsb + OFF_WOB;
    U16* qws = wsb + OFF_Q;
    U16* kws = wsb + OFF_K;
    U16* vws = wsb + OFF_V;
    U16* aws = wsb + OFF_AWS;   // aliases Xb (X dead after qkv_kernel)

    conv_kernel<<<dim3(10752), 256, 0, stream>>>(X, Wq, Wk, Wv, Wo, wsb);
    qkv_kernel<<<dim3(12, 64), 256, 0, stream>>>(Xb, Wqb, Wkb, Wvb, bq, bk, bv, cosT, sinT, qws, kws, vws);
    attn_kernel<<<dim3(16, 64), 256, 0, stream>>>(qws, kws, vws, aws);
    proj_kernel<<<dim3(8, 64), 256, 0, stream>>>(aws, Wob, bo, out);
}